// Round 8
// baseline (475.916 us; speedup 1.0000x reference)
//
#include <hip/hip_runtime.h>

// GraphAttentionLayer v10: B=16, M=2048, F_IN=128, F_OUT=64, ALPHA=0.2
// out = elu( softmax_j( mask(adj, leaky_relu(f1_i + f2_j)) ) @ (h@W) )
// Algebra: h' = ((P @ h) @ W)/den, f1 = h@(W@a1), f2 = h@(W@a2).
//
// v10 root cause: v5-v9 all ~160us in k_main regardless of scheduling.
// Common factor: the adj read pattern puts consecutive lanes 8 KB apart
// (16 rows x 128 B chunks per wave-load). Scatter-limited HBM service
// (~900 GB/s vs 6.7 TB/s for the contiguous fill on the same chip) +
// queue-inflated latency = the constant. No schedule fixes a pattern.
// Fix: THREE kernels, every hot load contiguous by construction:
//  k_prep : unchanged (hbf B-frags + f1all/f2all).
//  k_score: grid-stride streaming. Reads adj CONTIGUOUS (thread = 4
//           consecutive tokens, nt-loads: read-once), computes masked exp
//           scores, writes P (128 MB bf16) in MFMA-A-frag layout
//           [b][rg][tile][lc*4+quad] -> wave writes 8x contiguous 64-B
//           sectors. Zero dependent chains; pure BW.
//  k_main : drops adj/f1/f2/scores. Per tile: ONE contiguous 1-KB P-frag
//           load (permutation within 1KB window), 8 L2-hot bb loads,
//           den = 8 bf16 unpack-adds (same values+order -> bit-identical),
//           8 MFMAs. No manual scheduling anywhere.
// d_ws: hbf 8MB @0, f1all/f2all @8MB, P 128MB @16MB (fills show ws>=1GB).

#define M_     2048
#define FIN_   128
#define F_     64
#define ALPHA_ 0.2f
#define HS_    132     // k_prep LDS h-tile stride (floats)
#define WT_    132     // Tsum row stride (floats)

typedef float  float4_ __attribute__((ext_vector_type(4)));
typedef short  short8  __attribute__((ext_vector_type(8)));
typedef int    int4_   __attribute__((ext_vector_type(4)));
typedef unsigned int u32x4 __attribute__((ext_vector_type(4)));
typedef unsigned int u32x2 __attribute__((ext_vector_type(2)));
typedef unsigned short u16;
typedef unsigned int   u32;

// packed f32x2 -> bf16x2 (RNE)
static __device__ __forceinline__ u32 cvtpk(float lo, float hi) {
    u32 r;
    asm("v_cvt_pk_bf16_f32 %0, %1, %2" : "=v"(r) : "v"(lo), "v"(hi));
    return r;
}

// non-temporal 16B load (read-once stream, don't pollute L2/L3)
static __device__ __forceinline__ int4_ ntload4(const int* p) {
    return __builtin_nontemporal_load((const int4_*)p);
}

// ---------------------------------------------------------------------------
// Phase 1: hbf fragment layout: ((b*64 + t)*8 + nt)*64 + l  (16B per entry)
// ---------------------------------------------------------------------------
__global__ __launch_bounds__(256, 4) void k_prep(
    const float* __restrict__ h, const float* __restrict__ W,
    const float* __restrict__ a, u16* __restrict__ hbf,
    float* __restrict__ f1all, float* __restrict__ f2all)
{
    __shared__ float a_s[2 * F_];
    __shared__ float wa1[FIN_], wa2[FIN_];
    __shared__ float hs[32 * HS_];

    const int tid = threadIdx.x;
    const u32 bid = blockIdx.x;
    const u32 lg  = (bid & 7) * 128 + (bid >> 3);   // XCD x produces batches 2x,2x+1
    const int b   = lg >> 6;
    const int t   = lg & 63;

    if (tid < 128) a_s[tid] = a[tid];

    // h tile -> regs (coalesced float4)
    const int tok = tid >> 3, f0 = (tid & 7) * 16;
    const float* hp = h + ((size_t)(b * M_ + t * 32 + tok)) * FIN_ + f0;
    float4_ x0 = *(const float4_*)hp;
    float4_ x1 = *(const float4_*)(hp + 4);
    float4_ x2 = *(const float4_*)(hp + 8);
    float4_ x3 = *(const float4_*)(hp + 12);
    __syncthreads();   // a_s ready

    if (tid < FIN_) {
        float s1 = 0.f, s2 = 0.f;
#pragma unroll 8
        for (int n = 0; n < F_; ++n) {
            float wv = W[tid * F_ + n];
            s1 += wv * a_s[n];
            s2 += wv * a_s[F_ + n];
        }
        wa1[tid] = s1;
        wa2[tid] = s2;
    }

    float* hr = hs + tok * HS_ + f0;
    *(float4_*)(hr)      = x0;
    *(float4_*)(hr + 4)  = x1;
    *(float4_*)(hr + 8)  = x2;
    *(float4_*)(hr + 12) = x3;
    __syncthreads();   // hs + wa ready

    // ---- fragment conversion: thread handles lane l for nt0, nt0+1 ----
    {
        const int l = tid & 63, lc = l & 15, q = l >> 4;
        const int nt0 = (tid >> 6) * 2;
        u32x4* ob = (u32x4*)hbf + ((size_t)(b * 64 + t)) * 8 * 64;
#pragma unroll
        for (int ni = 0; ni < 2; ++ni) {
            const int nt = nt0 + ni;
            const float* cp = hs + (q * 8) * HS_ + nt * 16 + lc;
            u32x4 wv;
            wv[0] = cvtpk(cp[0 * HS_], cp[1 * HS_]);
            wv[1] = cvtpk(cp[2 * HS_], cp[3 * HS_]);
            wv[2] = cvtpk(cp[4 * HS_], cp[5 * HS_]);
            wv[3] = cvtpk(cp[6 * HS_], cp[7 * HS_]);
            ob[nt * 64 + l] = wv;
        }
    }

    // ---- f1/f2 per token (same reduction order as v9) ----
    {
        const int r = tid >> 3, k0 = (tid & 7) * 16;
        const float* rp = hs + r * HS_ + k0;
        float s1 = 0.f, s2 = 0.f;
#pragma unroll
        for (int k = 0; k < 16; ++k) {
            s1 += rp[k] * wa1[k0 + k];
            s2 += rp[k] * wa2[k0 + k];
        }
        s1 += __shfl_xor(s1, 1, 64); s2 += __shfl_xor(s2, 1, 64);
        s1 += __shfl_xor(s1, 2, 64); s2 += __shfl_xor(s2, 2, 64);
        s1 += __shfl_xor(s1, 4, 64); s2 += __shfl_xor(s2, 4, 64);
        if ((tid & 7) == 0) {
            f1all[b * M_ + t * 32 + r] = s1;
            f2all[b * M_ + t * 32 + r] = s2;
        }
    }
}

// ---------------------------------------------------------------------------
// Phase 2: P = masked exp scores in MFMA-A-frag layout. Pure streaming.
// e = (b*2048 + i)*512 + l4 : thread handles tokens 4*l4 .. +3 of row i.
// adj read contiguous (wave = dense 1 KB); P write = 64-B sectors.
// P entry (16 B) = tokens [tile*32 + quad*8 .. +7] of row i as 8 bf16;
// entry index = ((b*128 + i>>4)*64 + tile)*64 + (i&15)*4 + quad.
// ---------------------------------------------------------------------------
__global__ __launch_bounds__(256, 4) void k_score(
    const int* __restrict__ adj, const float* __restrict__ f1all,
    const float* __restrict__ f2all, u16* __restrict__ P)
{
    const u32 stride = 2048 * 256;
    u32 e = blockIdx.x * 256 + threadIdx.x;
#pragma unroll 2
    for (int it = 0; it < 32; ++it, e += stride) {
        const u32 b  = e >> 20;
        const u32 l4 = e & 511;

        int4_ c4 = ntload4(adj + (size_t)e * 4);
        const float f1v = f1all[e >> 9];
        float4_ g = *(const float4_*)(f2all + (b << 11) + l4 * 4);

        float x0 = f1v + g[0]; x0 = fmaxf(x0, ALPHA_ * x0);
        float x1 = f1v + g[1]; x1 = fmaxf(x1, ALPHA_ * x1);
        float x2 = f1v + g[2]; x2 = fmaxf(x2, ALPHA_ * x2);
        float x3 = f1v + g[3]; x3 = fmaxf(x3, ALPHA_ * x3);
        float e0 = (c4[0] > 0) ? __expf(x0) : 0.f;
        float e1 = (c4[1] > 0) ? __expf(x1) : 0.f;
        float e2 = (c4[2] > 0) ? __expf(x2) : 0.f;
        float e3 = (c4[3] > 0) ? __expf(x3) : 0.f;
        u32x2 pk;
        pk[0] = cvtpk(e0, e1);
        pk[1] = cvtpk(e2, e3);

        const u32 row  = (e >> 9) & 2047;
        const u32 rg   = row >> 4, lc = row & 15;
        const u32 tile = l4 >> 3;
        const u32 quad = (l4 >> 1) & 3;
        const u32 half = l4 & 1;
        const u32 pe   = ((((b << 7) + rg) << 6) + tile) * 64 + (lc << 2) + quad;
        *(u32x2*)((u32*)(P + (size_t)pe * 8) + half * 2) = pk;
    }
}

// ---------------------------------------------------------------------------
// Phase 3: 1024 blocks x 256 thr (4 waves). Wave (wr, wh): rows wr-group,
// token half wh (32 tiles). Per tile: 1 contiguous P-frag load + 8 bb +
// den unpack + 8 MFMA. No adj, no scores, no barriers in loop.
// ---------------------------------------------------------------------------
__global__ __launch_bounds__(256, 4) void k_main(
    const u16* __restrict__ P, const u16* __restrict__ hbf,
    const float* __restrict__ W, float* __restrict__ out)
{
    __shared__ float Tsum[32 * WT_];
    __shared__ float dens2[64];

    const int tid  = threadIdx.x;
    const int w    = tid >> 6;
    const int l    = tid & 63;
    const int lc   = l & 15;
    const int quad = l >> 4;
    const int wr   = w & 1;      // row group (16 rows)
    const int wh   = w >> 1;     // token half (32 tiles)

    const u32 bid = blockIdx.x;
    const u32 lg  = (bid & 7) * 128 + (bid >> 3);   // XCD x consumes batches 2x,2x+1
    const int b   = lg >> 6;
    const int i0  = (lg & 63) * 32;
    const int rgw = (lg & 63) * 2 + wr;             // this wave's row group

    const u32x4* pb = (const u32x4*)P
                    + (((size_t)((b << 7) + rgw)) << 12) + (lc << 2) + quad;
    const u32x4* hb = (const u32x4*)hbf + ((size_t)b * 64) * 8 * 64 + l;

    const int t0 = wh * 32;

    float denacc = 0.f;
    float4_ acc[8];
#pragma unroll
    for (int nt = 0; nt < 8; ++nt) acc[nt] = (float4_){0.f, 0.f, 0.f, 0.f};

    for (int k = 0; k < 32; ++k) {
        const int t = t0 + k;

        // A-fragment: one contiguous-window 16-B load per lane
        u32x4 pv = pb[(size_t)t << 6];
        // B-fragments (L2-hot)
        u32x4 bb[8];
#pragma unroll
        for (int nt = 0; nt < 8; ++nt) bb[nt] = hb[(t * 8 + nt) * 64];

        // den: unpack-add the 8 bf16 in token order (identical to v9's SC)
        float d = 0.f;
#pragma unroll
        for (int kk = 0; kk < 4; ++kk) {
            d += __uint_as_float(pv[kk] << 16);
            d += __uint_as_float(pv[kk] & 0xFFFF0000u);
        }
        denacc += d;

        const short8 af = __builtin_bit_cast(short8, pv);
#pragma unroll
        for (int nt = 0; nt < 8; ++nt)
            acc[nt] = __builtin_amdgcn_mfma_f32_16x16x32_bf16(
                af, __builtin_bit_cast(short8, bb[nt]), acc[nt], 0, 0, 0);
    }

    // ---- denom: reduce over the 4 quads; one slot per (wh, row) ----
    denacc += __shfl_xor(denacc, 16, 64);
    denacc += __shfl_xor(denacc, 32, 64);
    if (quad == 0) dens2[wh * 32 + wr * 16 + lc] = denacc;
    __syncthreads();

    // ---- merge token-half partials: wh0 writes, wh1 adds ----
    if (wh == 0) {
#pragma unroll
        for (int nt = 0; nt < 8; ++nt)
#pragma unroll
            for (int mm = 0; mm < 4; ++mm)
                Tsum[(wr * 16 + quad * 4 + mm) * WT_ + nt * 16 + lc] = acc[nt][mm];
    }
    __syncthreads();
    if (wh == 1) {
#pragma unroll
        for (int nt = 0; nt < 8; ++nt)
#pragma unroll
            for (int mm = 0; mm < 4; ++mm)
                Tsum[(wr * 16 + quad * 4 + mm) * WT_ + nt * 16 + lc] += acc[nt][mm];
    }
    __syncthreads();

    // ---- epilogue: out = elu( (T @ W_fp32) / den ), 32 rows ----
    {
        const int r  = tid >> 3;
        const int n0 = (tid & 7) * 8;
        const float den  = dens2[r] + dens2[32 + r];
        const float rden = (den > 0.f) ? (1.f / den) : 0.f;
        float u[8];
#pragma unroll
        for (int nn = 0; nn < 8; ++nn) u[nn] = 0.f;
#pragma unroll 4
        for (int k = 0; k < FIN_; ++k) {
            const float tv = Tsum[r * WT_ + k];
            float4_ wv0 = *(const float4_*)(W + k * F_ + n0);
            float4_ wv1 = *(const float4_*)(W + k * F_ + n0 + 4);
            u[0] += tv * wv0[0]; u[1] += tv * wv0[1];
            u[2] += tv * wv0[2]; u[3] += tv * wv0[3];
            u[4] += tv * wv1[0]; u[5] += tv * wv1[1];
            u[6] += tv * wv1[2]; u[7] += tv * wv1[3];
        }
        float4_ o0, o1;
#pragma unroll
        for (int nn = 0; nn < 8; ++nn) {
            float hp = u[nn] * rden;
            float o  = hp > 0.f ? hp : expm1f(hp);
            if (nn < 4) o0[nn] = o; else o1[nn - 4] = o;
        }
        float* op = out + ((size_t)(b * M_ + i0 + r)) * F_ + n0;
        *(float4_*)op       = o0;
        *(float4_*)(op + 4) = o1;
    }
}

// ---------------------------------------------------------------------------
extern "C" void kernel_launch(void* const* d_in, const int* in_sizes, int n_in,
                              void* d_out, int out_size, void* d_ws, size_t ws_size,
                              hipStream_t stream)
{
    (void)out_size; (void)ws_size;
    const float* h  = (const float*)d_in[0];
    const int* adjp = (const int*)d_in[1];
    const float* Wp = (const float*)d_in[2];
    const float* ap = (const float*)d_in[3];
    for (int i = 0; i < n_in; ++i) {
        long s = in_sizes[i];
        if      (s == 4194304L)  h    = (const float*)d_in[i];
        else if (s == 67108864L) adjp = (const int*)d_in[i];
        else if (s == 8192L)     Wp   = (const float*)d_in[i];
        else if (s == 128L)      ap   = (const float*)d_in[i];
    }
    u16*   hbf   = (u16*)d_ws;                                  // 8 MB
    float* f1all = (float*)((char*)d_ws + (8u << 20));          // 128 KB
    float* f2all = f1all + 16 * M_;                             // 128 KB
    u16*   Pp    = (u16*)((char*)d_ws + (16u << 20));           // 128 MB
    k_prep <<<1024, 256, 0, stream>>>(h, Wp, ap, hbf, f1all, f2all);
    k_score<<<2048, 256, 0, stream>>>(adjp, f1all, f2all, Pp);
    k_main <<<1024, 256, 0, stream>>>(Pp, hbf, Wp, (float*)d_out);
}

// Round 9
// 416.671 us; speedup vs baseline: 1.1422x; 1.1422x over previous
//
#include <hip/hip_runtime.h>

// GraphAttentionLayer v11: B=16, M=2048, F_IN=128, F_OUT=64, ALPHA=0.2
// out = elu( softmax_j( mask(adj, leaky_relu(f1_i + f2_j)) ) @ (h@W) )
// Algebra: h' = ((P @ h) @ W)/den, f1 = h@(W@a1), f2 = h@(W@a2).
//
// v11 root cause (from v10's decisive null): k_main stayed ~135us even with
// ALL loads contiguous -> adj scatter falsified. The invariant cost is the
// hbf B-frag re-read: 4096 waves x 256KB = 1 GB, served by L3 (~7.5 TB/s
// = ~135us) because the big per-version stream (adj or P) evicts hbf from
// the 4MB XCD L2 continuously. Fix: share B-frags across waves via LDS.
//  - block = 64 rows (4 waves x 16 rows); all waves consume the SAME tile
//    sequence; per tile the 8KB frag block is staged ONCE into ping-pong
//    LDS (thread: 2x16B contiguous), waves ds_read it (b128, 2-way free).
//    hbf traffic 1GB -> 256MB (L3, ~34us, overlapped under adj).
//  - adj back in-loop (v9 SC, 64B-segment pattern - exonerated by v10),
//    nt-loads, depth-2 static ping-pong.
//  - raw barrier per tile: lgkmcnt(0)+s_barrier only, NO vmcnt drain; stage
//    loads pinned at region top via sched_barrier(0), ds_write late ->
//    auto-wait is counted vmcnt(2), adj prefetch stays in flight.
//  - 2 blocks/CU: barrier-stalled block covered by the other.
// k_score deleted; k_prep unchanged. Numerics identical to v9.

#define M_     2048
#define FIN_   128
#define F_     64
#define ALPHA_ 0.2f
#define HS_    132     // k_prep LDS h-tile stride (floats)
#define WT_    132     // Tsum row stride (floats)

typedef float  float4_ __attribute__((ext_vector_type(4)));
typedef short  short8  __attribute__((ext_vector_type(8)));
typedef int    int4_   __attribute__((ext_vector_type(4)));
typedef unsigned int u32x4 __attribute__((ext_vector_type(4)));
typedef unsigned short u16;
typedef unsigned int   u32;

// packed f32x2 -> bf16x2 (RNE)
static __device__ __forceinline__ u32 cvtpk(float lo, float hi) {
    u32 r;
    asm("v_cvt_pk_bf16_f32 %0, %1, %2" : "=v"(r) : "v"(lo), "v"(hi));
    return r;
}

// non-temporal 16B load (read-once stream; reduce L2 pollution)
static __device__ __forceinline__ int4_ ntload4(const int* p) {
    return __builtin_nontemporal_load((const int4_*)p);
}

// ---------------------------------------------------------------------------
// Phase 1: hbf fragment layout: ((b*64 + t)*8 + nt)*64 + l  (16B per entry)
//   lane l of a wave holds B[n = nt*16 + (l&15)][k = (l>>4)*8 .. +7]
// ---------------------------------------------------------------------------
__global__ __launch_bounds__(256, 4) void k_prep(
    const float* __restrict__ h, const float* __restrict__ W,
    const float* __restrict__ a, u16* __restrict__ hbf,
    float* __restrict__ f1all, float* __restrict__ f2all)
{
    __shared__ float a_s[2 * F_];
    __shared__ float wa1[FIN_], wa2[FIN_];
    __shared__ float hs[32 * HS_];

    const int tid = threadIdx.x;
    const u32 bid = blockIdx.x;
    const u32 lg  = (bid & 7) * 128 + (bid >> 3);   // XCD x produces batches 2x,2x+1
    const int b   = lg >> 6;
    const int t   = lg & 63;

    if (tid < 128) a_s[tid] = a[tid];

    // h tile -> regs (coalesced float4)
    const int tok = tid >> 3, f0 = (tid & 7) * 16;
    const float* hp = h + ((size_t)(b * M_ + t * 32 + tok)) * FIN_ + f0;
    float4_ x0 = *(const float4_*)hp;
    float4_ x1 = *(const float4_*)(hp + 4);
    float4_ x2 = *(const float4_*)(hp + 8);
    float4_ x3 = *(const float4_*)(hp + 12);
    __syncthreads();   // a_s ready

    if (tid < FIN_) {
        float s1 = 0.f, s2 = 0.f;
#pragma unroll 8
        for (int n = 0; n < F_; ++n) {
            float wv = W[tid * F_ + n];
            s1 += wv * a_s[n];
            s2 += wv * a_s[F_ + n];
        }
        wa1[tid] = s1;
        wa2[tid] = s2;
    }

    float* hr = hs + tok * HS_ + f0;
    *(float4_*)(hr)      = x0;
    *(float4_*)(hr + 4)  = x1;
    *(float4_*)(hr + 8)  = x2;
    *(float4_*)(hr + 12) = x3;
    __syncthreads();   // hs + wa ready

    // ---- fragment conversion: thread handles lane l for nt0, nt0+1 ----
    {
        const int l = tid & 63, lc = l & 15, q = l >> 4;
        const int nt0 = (tid >> 6) * 2;
        u32x4* ob = (u32x4*)hbf + ((size_t)(b * 64 + t)) * 8 * 64;
#pragma unroll
        for (int ni = 0; ni < 2; ++ni) {
            const int nt = nt0 + ni;
            const float* cp = hs + (q * 8) * HS_ + nt * 16 + lc;
            u32x4 wv;
            wv[0] = cvtpk(cp[0 * HS_], cp[1 * HS_]);
            wv[1] = cvtpk(cp[2 * HS_], cp[3 * HS_]);
            wv[2] = cvtpk(cp[4 * HS_], cp[5 * HS_]);
            wv[3] = cvtpk(cp[6 * HS_], cp[7 * HS_]);
            ob[nt * 64 + l] = wv;
        }
    }

    // ---- f1/f2 per token (same reduction order as v9/v10) ----
    {
        const int r = tid >> 3, k0 = (tid & 7) * 16;
        const float* rp = hs + r * HS_ + k0;
        float s1 = 0.f, s2 = 0.f;
#pragma unroll
        for (int k = 0; k < 16; ++k) {
            s1 += rp[k] * wa1[k0 + k];
            s2 += rp[k] * wa2[k0 + k];
        }
        s1 += __shfl_xor(s1, 1, 64); s2 += __shfl_xor(s2, 1, 64);
        s1 += __shfl_xor(s1, 2, 64); s2 += __shfl_xor(s2, 2, 64);
        s1 += __shfl_xor(s1, 4, 64); s2 += __shfl_xor(s2, 4, 64);
        if ((tid & 7) == 0) {
            f1all[b * M_ + t * 32 + r] = s1;
            f2all[b * M_ + t * 32 + r] = s2;
        }
    }
}

// ---------------------------------------------------------------------------
// Phase 2: 512 blocks x 256 thr (4 waves x 16 rows = 64 rows). All waves
// consume the same tile each iter; B-frags staged once/block into ping-pong
// LDS. One raw barrier per tile (no vmcnt drain).
// ---------------------------------------------------------------------------
__global__ __launch_bounds__(256, 2) void k_main(
    const int* __restrict__ adj, const u16* __restrict__ hbf,
    const float* __restrict__ f1all, const float* __restrict__ f2all,
    const float* __restrict__ W, float* __restrict__ out)
{
    __shared__ char  dyn[64 * WT_ * 4];   // 33792: bufs 16K + f2s 8K / Tsum alias
    __shared__ float dens[64];

    u32x4* lbuf = (u32x4*)dyn;            // 2 x 512-entry tile buffers (16 KB)
    float* f2s  = (float*)(dyn + 16384);  // [2048] 8 KB
    float* Tsum = (float*)dyn;            // [64][WT_] (epilogue only)

    const int tid  = threadIdx.x;
    const int w    = tid >> 6;
    const int l    = tid & 63;
    const int lc   = l & 15;
    const int quad = l >> 4;

    const u32 bid = blockIdx.x;
    const u32 lg  = (bid & 7) * 64 + (bid >> 3);    // XCD x consumes batches 2x,2x+1
    const int b   = lg >> 5;
    const int i0  = (lg & 31) * 64;

    // stage f2all[b] -> LDS (8 KB, broadcast-read in loop)
    {
        const int o = tid * 8;
        float4_ v0 = *(const float4_*)(f2all + b * M_ + o);
        float4_ v1 = *(const float4_*)(f2all + b * M_ + o + 4);
        *(float4_*)(f2s + o)     = v0;
        *(float4_*)(f2s + o + 4) = v1;
    }

    const float f1r = f1all[b * M_ + i0 + w * 16 + lc];
    const int* aprow = adj + ((size_t)(b * M_ + i0 + w * 16 + lc)) * M_ + quad * 8;
    const u32x4* hbs = (const u32x4*)hbf + (size_t)b * 32768;   // 64*8*64 entries

    // stage tile 0 -> buf0 (each thread 2x16B, contiguous)
    {
        u32x4 s0 = hbs[tid];
        u32x4 s1 = hbs[256 + tid];
        lbuf[tid]       = s0;
        lbuf[256 + tid] = s1;
    }
    // adj prefetch: tiles 0,1 (depth-2 static ping-pong)
    int4_ aA0 = ntload4(aprow);
    int4_ aA1 = ntload4(aprow + 4);
    int4_ aB0 = ntload4(aprow + 32);
    int4_ aB1 = ntload4(aprow + 36);

    __syncthreads();   // f2s + buf0 ready (one-time full drain, prologue only)

    float denacc = 0.f;
    float4_ acc[8];
#pragma unroll
    for (int nt = 0; nt < 8; ++nt) acc[nt] = (float4_){0.f, 0.f, 0.f, 0.f};

#define SC(GE, GO, AE, AO, IDX)                                 \
        {                                                       \
            float xe = f1r + (GE); xe = fmaxf(xe, ALPHA_ * xe); \
            float xo = f1r + (GO); xo = fmaxf(xo, ALPHA_ * xo); \
            float ee = ((AE) > 0) ? __expf(xe) : 0.f;           \
            float eo = ((AO) > 0) ? __expf(xo) : 0.f;           \
            u32 pk = cvtpk(ee, eo);                             \
            d += __uint_as_float(pk << 16);                     \
            d += __uint_as_float(pk & 0xFFFF0000u);             \
            pw[IDX] = pk;                                       \
        }

// Per tile T (consumes adj regs A0/A1 = tile T, reloads them with T+2):
//  1. issue stage loads for tile T+1 (oldest VMEM of the iter; SB(0) pins)
//  2. ds_read current buf (8 x b128, conflict-free, shared by all 4 waves)
//  3. scores from A0/A1 + f2s; den
//  4. adj reload (tile T+2, nt)
//  5. 8 MFMA
//  6. SB(0); ds_write next buf (auto-wait = counted vmcnt(2): only the adj
//     reload is newer -> stage data drained, adj stays in flight)
//  7. lgkmcnt(0) + raw s_barrier (ds ops visible; NO vmcnt drain)
#define STAGE(T, A0, A1)                                                      \
    {                                                                         \
        const int ts = ((T) < 63) ? (T) + 1 : 63;                             \
        const int tp = ((T) < 62) ? (T) + 2 : 63;                             \
        u32x4 s0 = hbs[ts * 512 + tid];                                       \
        u32x4 s1 = hbs[ts * 512 + 256 + tid];                                 \
        __builtin_amdgcn_sched_barrier(0);                                    \
        const u32x4* lc_ = lbuf + ((T) & 1) * 512;                            \
        u32x4 bb[8];                                                          \
        _Pragma("unroll")                                                     \
        for (int nt = 0; nt < 8; ++nt) bb[nt] = lc_[nt * 64 + l];             \
        float4_ g0 = *(const float4_*)(f2s + (T) * 32 + quad * 8);            \
        float4_ g1 = *(const float4_*)(f2s + (T) * 32 + quad * 8 + 4);        \
        u32x4 pw;                                                             \
        float d = 0.f;                                                        \
        SC(g0[0], g0[1], A0[0], A0[1], 0)                                     \
        SC(g0[2], g0[3], A0[2], A0[3], 1)                                     \
        SC(g1[0], g1[1], A1[0], A1[1], 2)                                     \
        SC(g1[2], g1[3], A1[2], A1[3], 3)                                     \
        denacc += d;                                                          \
        const short8 af = __builtin_bit_cast(short8, pw);                     \
        A0 = ntload4(aprow + tp * 32);                                        \
        A1 = ntload4(aprow + tp * 32 + 4);                                    \
        _Pragma("unroll")                                                     \
        for (int nt = 0; nt < 8; ++nt)                                        \
            acc[nt] = __builtin_amdgcn_mfma_f32_16x16x32_bf16(                \
                af, __builtin_bit_cast(short8, bb[nt]), acc[nt], 0, 0, 0);    \
        __builtin_amdgcn_sched_barrier(0);                                    \
        u32x4* ln_ = lbuf + (((T) + 1) & 1) * 512;                            \
        ln_[tid]       = s0;                                                  \
        ln_[256 + tid] = s1;                                                  \
        asm volatile("s_waitcnt lgkmcnt(0)" ::: "memory");                    \
        __builtin_amdgcn_s_barrier();                                         \
        __builtin_amdgcn_sched_barrier(0);                                    \
    }

    for (int o2 = 0; o2 < 32; ++o2) {
        STAGE(2 * o2,     aA0, aA1)
        STAGE(2 * o2 + 1, aB0, aB1)
    }
#undef STAGE
#undef SC

    // ---- denom: reduce over the 4 quads ----
    denacc += __shfl_xor(denacc, 16, 64);
    denacc += __shfl_xor(denacc, 32, 64);
    if (quad == 0) dens[w * 16 + lc] = denacc;
    __syncthreads();   // loop LDS dead; Tsum alias safe

    // ---- T -> LDS (disjoint per wave: wave w owns rows w*16..+15) ----
#pragma unroll
    for (int nt = 0; nt < 8; ++nt)
#pragma unroll
        for (int mm = 0; mm < 4; ++mm)
            Tsum[(w * 16 + quad * 4 + mm) * WT_ + nt * 16 + lc] = acc[nt][mm];
    __syncthreads();

    // ---- epilogue: out = elu( (T @ W_fp32) / den ), 64 rows in 2 passes ----
#pragma unroll
    for (int rr = 0; rr < 2; ++rr) {
        const int r  = (tid >> 3) + rr * 32;
        const int n0 = (tid & 7) * 8;
        const float den  = dens[r];
        const float rden = (den > 0.f) ? (1.f / den) : 0.f;
        float u[8];
#pragma unroll
        for (int nn = 0; nn < 8; ++nn) u[nn] = 0.f;
#pragma unroll 4
        for (int k = 0; k < FIN_; ++k) {
            const float tv = Tsum[r * WT_ + k];
            float4_ wv0 = *(const float4_*)(W + k * F_ + n0);
            float4_ wv1 = *(const float4_*)(W + k * F_ + n0 + 4);
            u[0] += tv * wv0[0]; u[1] += tv * wv0[1];
            u[2] += tv * wv0[2]; u[3] += tv * wv0[3];
            u[4] += tv * wv1[0]; u[5] += tv * wv1[1];
            u[6] += tv * wv1[2]; u[7] += tv * wv1[3];
        }
        float4_ o0, o1;
#pragma unroll
        for (int nn = 0; nn < 8; ++nn) {
            float hp = u[nn] * rden;
            float o  = hp > 0.f ? hp : expm1f(hp);
            if (nn < 4) o0[nn] = o; else o1[nn - 4] = o;
        }
        float* op = out + ((size_t)(b * M_ + i0 + r)) * F_ + n0;
        *(float4_*)op       = o0;
        *(float4_*)(op + 4) = o1;
    }
}

// ---------------------------------------------------------------------------
extern "C" void kernel_launch(void* const* d_in, const int* in_sizes, int n_in,
                              void* d_out, int out_size, void* d_ws, size_t ws_size,
                              hipStream_t stream)
{
    (void)out_size; (void)ws_size;
    const float* h  = (const float*)d_in[0];
    const int* adjp = (const int*)d_in[1];
    const float* Wp = (const float*)d_in[2];
    const float* ap = (const float*)d_in[3];
    for (int i = 0; i < n_in; ++i) {
        long s = in_sizes[i];
        if      (s == 4194304L)  h    = (const float*)d_in[i];
        else if (s == 67108864L) adjp = (const int*)d_in[i];
        else if (s == 8192L)     Wp   = (const float*)d_in[i];
        else if (s == 128L)      ap   = (const float*)d_in[i];
    }
    u16*   hbf   = (u16*)d_ws;                                  // 8 MB
    float* f1all = (float*)((char*)d_ws + (8u << 20));          // 128 KB
    float* f2all = f1all + 16 * M_;                             // 128 KB
    k_prep<<<1024, 256, 0, stream>>>(h, Wp, ap, hbf, f1all, f2all);
    k_main<<<512, 256, 0, stream>>>(adjp, hbf, f1all, f2all, Wp, (float*)d_out);
}